// Round 14
// baseline (77.360 us; speedup 1.0000x reference)
//
#include <hip/hip_runtime.h>
#include <hip/hip_bf16.h>
#include <math.h>

#define N_ROWS 8192   // SIZE
#define N_COLS 1024   // M
#define NBLK   256    // 1 block/CU (coop-validated geometry, round 6)
#define NTHR   1024

typedef float f32x4 __attribute__((ext_vector_type(4)));  // native vec for nontemporal builtin

// Manual grid barrier: ticket counter in ws (memset to 0 each call).
// Release (threadfence) -> device-scope add -> t0 acquire-spin -> syncthreads.
__device__ __forceinline__ void grid_barrier(unsigned* ctr, unsigned target) {
    __syncthreads();
    if (threadIdx.x == 0) {
        __threadfence();  // release: ps/S writes visible device-wide
        __hip_atomic_fetch_add(ctr, 1u, __ATOMIC_ACQ_REL, __HIP_MEMORY_SCOPE_AGENT);
        while (__hip_atomic_load(ctr, __ATOMIC_ACQUIRE, __HIP_MEMORY_SCOPE_AGENT) < target) {
            __builtin_amdgcn_s_sleep(2);
        }
    }
    __syncthreads();
}

// Single dispatch: phase1 (x -> exp -> LDS + bf16 ps) | bar | phase2 (8 blocks
// reduce ps -> S, coalesced stripes) | bar | phase3 (finalize from LDS, NT stores).
__global__ __launch_bounds__(NTHR) void fused_manual(
    const float* __restrict__ x, const float* __restrict__ diag,
    __hip_bfloat16* __restrict__ ps, float* __restrict__ S,
    unsigned* __restrict__ ctr, float* __restrict__ out)
{
    __shared__ float ex[32][N_COLS];    // 128 KB exp(x) tile, live across barriers
    __shared__ float red[4][N_COLS];    // 16 KB scratch (phase1 + phase2 reuse)

    const int t    = threadIdx.x;
    const int b    = blockIdx.x;
    const int col0 = (t & 255) * 4;
    const int rg   = t >> 8;            // 0..3
    const int r0   = rg * 8;
    const int row0 = b * 32 + r0;

    // ---- Phase 1: read x once, exp -> LDS, block column partials -> ps ----
    float4 s4 = make_float4(0.f, 0.f, 0.f, 0.f);
#pragma unroll
    for (int k = 0; k < 8; ++k) {
        const float4 v = *reinterpret_cast<const float4*>(
            x + (size_t)(row0 + k) * N_COLS + col0);
        float4 e;
        e.x = __expf(v.x); e.y = __expf(v.y);
        e.z = __expf(v.z); e.w = __expf(v.w);
        *reinterpret_cast<float4*>(&ex[r0 + k][col0]) = e;
        s4.x += e.x; s4.y += e.y; s4.z += e.z; s4.w += e.w;
    }
    *reinterpret_cast<float4*>(&red[rg][col0]) = s4;
    __syncthreads();
    const float sc = red[0][t] + red[1][t] + red[2][t] + red[3][t];
    ps[(size_t)b * N_COLS + t] = __float2bfloat16(sc);

    grid_barrier(ctr, NBLK);            // ps visible everywhere

    // ---- Phase 2: blocks 0..7 reduce ps -> S (128-col stripe each) ----
    if (b < 8) {
        float (*red2)[128] = reinterpret_cast<float (*)[128]>(&red[0][0]);  // 8 KB of red
        const int cg = t >> 6;          // chunk-group 0..15 (16 chunks each)
        const int cp = t & 63;          // col-pair within stripe
        const __hip_bfloat162* ps2 = reinterpret_cast<const __hip_bfloat162*>(ps);
        float s0 = 0.f, s1 = 0.f;
#pragma unroll 8
        for (int k = 0; k < 16; ++k) {
            const __hip_bfloat162 p =
                ps2[(size_t)(cg * 16 + k) * (N_COLS / 2) + b * 64 + cp];
            s0 += __bfloat162float(p.x);
            s1 += __bfloat162float(p.y);
        }
        red2[cg][2 * cp]     = s0;
        red2[cg][2 * cp + 1] = s1;
        __syncthreads();
        if (t < 128) {
            float s = 0.f;
#pragma unroll
            for (int g = 0; g < 16; ++g) s += red2[g][t];
            S[b * 128 + t] = s;
        }
    }

    grid_barrier(ctr, 2 * NBLK);        // S visible everywhere

    // ---- Phase 3: finalize from LDS tile, nontemporal stores ----
    const float4 Sj = *reinterpret_cast<const float4*>(S + col0);
#pragma unroll
    for (int k = 0; k < 8; ++k) {
        const int row = row0 + k;
        const float E = __expf(diag[row]) - 1.f;   // wave-uniform
        const float4 e = *reinterpret_cast<const float4*>(&ex[r0 + k][col0]);
        f32x4 o;
        o.x = __logf(fmaf(E, e.x, Sj.x));
        o.y = __logf(fmaf(E, e.y, Sj.y));
        o.z = __logf(fmaf(E, e.z, Sj.z));
        o.w = __logf(fmaf(E, e.w, Sj.w));
        __builtin_nontemporal_store(
            o, reinterpret_cast<f32x4*>(out + (size_t)row * N_COLS + col0));
    }
}

// ---------------- Fallback (round-12 exact, proven 24.7 us) ----------------

__global__ __launch_bounds__(1024) void colsum_part(
    const float* __restrict__ x, __hip_bfloat16* __restrict__ ps) {
    const int b    = blockIdx.x;
    const int t    = threadIdx.x;
    const int col0 = (t & 255) * 4;
    const int rg   = t >> 8;
    const int row0 = b * 32 + rg * 8;

    float4 s4 = make_float4(0.f, 0.f, 0.f, 0.f);
#pragma unroll
    for (int k = 0; k < 8; ++k) {
        const float4 v = *reinterpret_cast<const float4*>(
            x + (size_t)(row0 + k) * N_COLS + col0);
        s4.x += __expf(v.x); s4.y += __expf(v.y);
        s4.z += __expf(v.z); s4.w += __expf(v.w);
    }
    __shared__ float red[4][N_COLS];
    *reinterpret_cast<float4*>(&red[rg][col0]) = s4;
    __syncthreads();
    const float s = red[0][t] + red[1][t] + red[2][t] + red[3][t];
    ps[(size_t)b * N_COLS + t] = __float2bfloat16(s);
}

__global__ __launch_bounds__(1024) void merge_finalize(
    const float* __restrict__ x, const float* __restrict__ diag,
    const __hip_bfloat16* __restrict__ ps, float* __restrict__ out) {
    const int cs = blockIdx.x & 7;
    const int rb = blockIdx.x >> 3;
    const int c0 = cs * 128;
    const int t  = threadIdx.x;

    __shared__ float red[16][128];
    __shared__ float S[128];
    {
        const int cg = t >> 6;
        const int cp = t & 63;
        const __hip_bfloat162* ps2 = reinterpret_cast<const __hip_bfloat162*>(ps);
        float s0 = 0.f, s1 = 0.f;
#pragma unroll 8
        for (int k = 0; k < 16; ++k) {
            const __hip_bfloat162 p =
                ps2[(size_t)(cg * 16 + k) * (N_COLS / 2) + cs * 64 + cp];
            s0 += __bfloat162float(p.x);
            s1 += __bfloat162float(p.y);
        }
        red[cg][2 * cp]     = s0;
        red[cg][2 * cp + 1] = s1;
    }
    __syncthreads();
    if (t < 128) {
        float s = 0.f;
#pragma unroll
        for (int g = 0; g < 16; ++g) s += red[g][t];
        S[t] = s;
    }
    __syncthreads();

    const int rr = t >> 5;
    const int cv = t & 31;
    const int col = c0 + 4 * cv;
    const float4 Sj = *reinterpret_cast<const float4*>(&S[4 * cv]);
    const int r0 = rb * 256 + rr;

#pragma unroll
    for (int k = 0; k < 8; ++k) {
        const int row = r0 + k * 32;
        const float E = __expf(diag[row]) - 1.f;
        const size_t off = (size_t)row * N_COLS + col;
        const float4 v = *reinterpret_cast<const float4*>(x + off);
        f32x4 o;
        o.x = __logf(fmaf(E, __expf(v.x), Sj.x));
        o.y = __logf(fmaf(E, __expf(v.y), Sj.y));
        o.z = __logf(fmaf(E, __expf(v.z), Sj.z));
        o.w = __logf(fmaf(E, __expf(v.w), Sj.w));
        __builtin_nontemporal_store(o, reinterpret_cast<f32x4*>(out + off));
    }
}

extern "C" void kernel_launch(void* const* d_in, const int* in_sizes, int n_in,
                              void* d_out, int out_size, void* d_ws, size_t ws_size,
                              hipStream_t stream) {
    const float* x    = (const float*)d_in[0];   // [8192, 1024] f32
    const float* diag = (const float*)d_in[1];   // [8192] f32
    float* out = (float*)d_out;                  // [8192, 1024] f32

    // ws layout: [ctr 16B pad][ps 512KB bf16][S 4KB f32]
    unsigned* ctr = (unsigned*)d_ws;
    __hip_bfloat16* ps = (__hip_bfloat16*)((char*)d_ws + 16);
    float* S = (float*)((char*)d_ws + 16 + (size_t)NBLK * N_COLS * 2);

    hipMemsetAsync(ctr, 0, sizeof(unsigned), stream);   // async: capture-safe

    void* args[] = { (void*)&x, (void*)&diag, (void*)&ps, (void*)&S,
                     (void*)&ctr, (void*)&out };
    hipError_t err = hipLaunchCooperativeKernel((const void*)fused_manual,
                                                dim3(NBLK), dim3(NTHR), args, 0, stream);
    if (err != hipSuccess) {
        colsum_part<<<256, 1024, 0, stream>>>(x, ps);
        merge_finalize<<<256, 1024, 0, stream>>>(x, diag, ps, out);
    }
}

// Round 15
// 24.990 us; speedup vs baseline: 3.0956x; 3.0956x over previous
//
#include <hip/hip_runtime.h>
#include <hip/hip_bf16.h>
#include <hip/hip_fp8.h>
#include <math.h>

#define N_ROWS 8192   // SIZE
#define N_COLS 1024   // M

typedef float f32x4 __attribute__((ext_vector_type(4)));  // native vec for nontemporal builtin

__device__ __forceinline__ unsigned char f32_to_fp8(float f) {
    return (unsigned char)__hip_cvt_float_to_fp8(f, __HIP_SATFINITE, __HIP_E4M3);
}
__device__ __forceinline__ float fp8_to_f32(unsigned char b) {
    __half_raw hr = __hip_cvt_fp8_to_halfraw((__hip_fp8_storage_t)b, __HIP_E4M3);
    return __half2float(__half(hr));
}

// ---------------- Primary path: fp8 e + bf16 ps ----------------

// K1q: ps[b][j] = bf16( sum_{i in [32b,32b+32)} exp(x[i][j]) );
//      pe[i][j] = fp8_e4m3(exp(x[i][j]))  (8 MB total, K2 never re-reads x).
__global__ __launch_bounds__(1024) void colsum_part_q(
    const float* __restrict__ x, __hip_bfloat16* __restrict__ ps,
    uchar4* __restrict__ pe4) {
    const int b    = blockIdx.x;
    const int t    = threadIdx.x;
    const int col0 = (t & 255) * 4;
    const int rg   = t >> 8;            // 0..3
    const int row0 = b * 32 + rg * 8;

    float4 s4 = make_float4(0.f, 0.f, 0.f, 0.f);
#pragma unroll
    for (int k = 0; k < 8; ++k) {
        const int row = row0 + k;
        const float4 v = *reinterpret_cast<const float4*>(
            x + (size_t)row * N_COLS + col0);
        float4 e;
        e.x = __expf(v.x); e.y = __expf(v.y);
        e.z = __expf(v.z); e.w = __expf(v.w);
        uchar4 q;
        q.x = f32_to_fp8(e.x); q.y = f32_to_fp8(e.y);
        q.z = f32_to_fp8(e.z); q.w = f32_to_fp8(e.w);
        pe4[((size_t)row * N_COLS + col0) >> 2] = q;   // 256 B/wave contiguous
        s4.x += e.x; s4.y += e.y; s4.z += e.z; s4.w += e.w;
    }
    __shared__ float red[4][N_COLS];    // 16 KB
    *reinterpret_cast<float4*>(&red[rg][col0]) = s4;
    __syncthreads();
    const float s = red[0][t] + red[1][t] + red[2][t] + red[3][t];
    ps[(size_t)b * N_COLS + t] = __float2bfloat16(s);
}

// K2q: 8 col-stripes (128 cols) x 32 row-blocks (256 rows), 1024 threads.
// issue-early: pe rows k=0..3 + diag k=0..3 prefetched BEFORE phase A
// (latency hides under the ps reduce; only ~8 VGPR so no occupancy cliff).
__global__ __launch_bounds__(1024) void merge_finalize_q(
    const float* __restrict__ diag, const __hip_bfloat16* __restrict__ ps,
    const uchar4* __restrict__ pe4, float* __restrict__ out) {
    const int cs = blockIdx.x & 7;      // stripe 0..7
    const int rb = blockIdx.x >> 3;     // row-block 0..31
    const int c0 = cs * 128;
    const int t  = threadIdx.x;
    const int rr = t >> 5;              // row offset 0..31
    const int cv = t & 31;              // 4-col group within stripe
    const int col = c0 + 4 * cv;
    const int r0  = rb * 256 + rr;

    // ---- issue-early prefetch (4 pe rows + 4 diag): ~8 VGPR ----
    uchar4 p[4];
    float  dpre[4];
#pragma unroll
    for (int k = 0; k < 4; ++k) {
        p[k]    = pe4[((size_t)(r0 + k * 32) * N_COLS + col) >> 2];
        dpre[k] = diag[r0 + k * 32];
    }

    // ---- phase A: S[c] = column sums of bf16 ps (round-12 exact) ----
    __shared__ float red[16][128];      // 8 KB
    __shared__ float S[128];            // 512 B
    {
        const int cg = t >> 6;          // chunk-group 0..15 (16 chunks each)
        const int cp = t & 63;          // col-pair within stripe
        const __hip_bfloat162* ps2 = reinterpret_cast<const __hip_bfloat162*>(ps);
        float s0 = 0.f, s1 = 0.f;
#pragma unroll 8
        for (int k = 0; k < 16; ++k) {
            const __hip_bfloat162 pp =
                ps2[(size_t)(cg * 16 + k) * (N_COLS / 2) + cs * 64 + cp];
            s0 += __bfloat162float(pp.x);
            s1 += __bfloat162float(pp.y);
        }
        red[cg][2 * cp]     = s0;
        red[cg][2 * cp + 1] = s1;
    }
    __syncthreads();
    if (t < 128) {
        float s = 0.f;
#pragma unroll
        for (int g = 0; g < 16; ++g) s += red[g][t];
        S[t] = s;
    }
    __syncthreads();

    const float4 Sj = *reinterpret_cast<const float4*>(&S[4 * cv]);

    // ---- phase B: k=0..3 from prefetch, k=4..7 loaded inline ----
#pragma unroll
    for (int k = 0; k < 4; ++k) {
        const int row = r0 + k * 32;
        const float E = __expf(dpre[k]) - 1.f;
        f32x4 o;
        o.x = __logf(fmaf(E, fp8_to_f32(p[k].x), Sj.x));
        o.y = __logf(fmaf(E, fp8_to_f32(p[k].y), Sj.y));
        o.z = __logf(fmaf(E, fp8_to_f32(p[k].z), Sj.z));
        o.w = __logf(fmaf(E, fp8_to_f32(p[k].w), Sj.w));
        __builtin_nontemporal_store(
            o, reinterpret_cast<f32x4*>(out + (size_t)row * N_COLS + col));
    }
#pragma unroll
    for (int k = 4; k < 8; ++k) {
        const int row = r0 + k * 32;
        const uchar4 q = pe4[((size_t)row * N_COLS + col) >> 2];
        const float E = __expf(diag[row]) - 1.f;
        f32x4 o;
        o.x = __logf(fmaf(E, fp8_to_f32(q.x), Sj.x));
        o.y = __logf(fmaf(E, fp8_to_f32(q.y), Sj.y));
        o.z = __logf(fmaf(E, fp8_to_f32(q.z), Sj.z));
        o.w = __logf(fmaf(E, fp8_to_f32(q.w), Sj.w));
        __builtin_nontemporal_store(
            o, reinterpret_cast<f32x4*>(out + (size_t)row * N_COLS + col));
    }
}

// ---------------- Fallback (round-12 exact, proven 24.7 us) ----------------

__global__ __launch_bounds__(1024) void colsum_part(
    const float* __restrict__ x, __hip_bfloat16* __restrict__ ps) {
    const int b    = blockIdx.x;
    const int t    = threadIdx.x;
    const int col0 = (t & 255) * 4;
    const int rg   = t >> 8;
    const int row0 = b * 32 + rg * 8;

    float4 s4 = make_float4(0.f, 0.f, 0.f, 0.f);
#pragma unroll
    for (int k = 0; k < 8; ++k) {
        const float4 v = *reinterpret_cast<const float4*>(
            x + (size_t)(row0 + k) * N_COLS + col0);
        s4.x += __expf(v.x); s4.y += __expf(v.y);
        s4.z += __expf(v.z); s4.w += __expf(v.w);
    }
    __shared__ float red[4][N_COLS];
    *reinterpret_cast<float4*>(&red[rg][col0]) = s4;
    __syncthreads();
    const float s = red[0][t] + red[1][t] + red[2][t] + red[3][t];
    ps[(size_t)b * N_COLS + t] = __float2bfloat16(s);
}

__global__ __launch_bounds__(1024) void merge_finalize(
    const float* __restrict__ x, const float* __restrict__ diag,
    const __hip_bfloat16* __restrict__ ps, float* __restrict__ out) {
    const int cs = blockIdx.x & 7;
    const int rb = blockIdx.x >> 3;
    const int c0 = cs * 128;
    const int t  = threadIdx.x;

    __shared__ float red[16][128];
    __shared__ float S[128];
    {
        const int cg = t >> 6;
        const int cp = t & 63;
        const __hip_bfloat162* ps2 = reinterpret_cast<const __hip_bfloat162*>(ps);
        float s0 = 0.f, s1 = 0.f;
#pragma unroll 8
        for (int k = 0; k < 16; ++k) {
            const __hip_bfloat162 pp =
                ps2[(size_t)(cg * 16 + k) * (N_COLS / 2) + cs * 64 + cp];
            s0 += __bfloat162float(pp.x);
            s1 += __bfloat162float(pp.y);
        }
        red[cg][2 * cp]     = s0;
        red[cg][2 * cp + 1] = s1;
    }
    __syncthreads();
    if (t < 128) {
        float s = 0.f;
#pragma unroll
        for (int g = 0; g < 16; ++g) s += red[g][t];
        S[t] = s;
    }
    __syncthreads();

    const int rr = t >> 5;
    const int cv = t & 31;
    const int col = c0 + 4 * cv;
    const float4 Sj = *reinterpret_cast<const float4*>(&S[4 * cv]);
    const int r0 = rb * 256 + rr;

#pragma unroll
    for (int k = 0; k < 8; ++k) {
        const int row = r0 + k * 32;
        const float E = __expf(diag[row]) - 1.f;
        const size_t off = (size_t)row * N_COLS + col;
        const float4 v = *reinterpret_cast<const float4*>(x + off);
        f32x4 o;
        o.x = __logf(fmaf(E, __expf(v.x), Sj.x));
        o.y = __logf(fmaf(E, __expf(v.y), Sj.y));
        o.z = __logf(fmaf(E, __expf(v.z), Sj.z));
        o.w = __logf(fmaf(E, __expf(v.w), Sj.w));
        __builtin_nontemporal_store(o, reinterpret_cast<f32x4*>(out + off));
    }
}

extern "C" void kernel_launch(void* const* d_in, const int* in_sizes, int n_in,
                              void* d_out, int out_size, void* d_ws, size_t ws_size,
                              hipStream_t stream) {
    const float* x    = (const float*)d_in[0];   // [8192, 1024] f32
    const float* diag = (const float*)d_in[1];   // [8192] f32
    float* out = (float*)d_out;                  // [8192, 1024] f32

    __hip_bfloat16* ps = (__hip_bfloat16*)d_ws;  // 512 KB
    const size_t ps_bytes = (size_t)(256 * N_COLS) * 2;
    const size_t pe_bytes = (size_t)N_ROWS * N_COLS;      // 8 MB fp8
    if (ws_size >= ps_bytes + pe_bytes) {
        uchar4* pe4 = reinterpret_cast<uchar4*>((char*)d_ws + ps_bytes);
        colsum_part_q<<<256, 1024, 0, stream>>>(x, ps, pe4);
        merge_finalize_q<<<256, 1024, 0, stream>>>(diag, ps, pe4, out);
    } else {
        colsum_part<<<256, 1024, 0, stream>>>(x, ps);
        merge_finalize<<<256, 1024, 0, stream>>>(x, diag, ps, out);
    }
}

// Round 16
// 24.148 us; speedup vs baseline: 3.2036x; 1.0349x over previous
//
#include <hip/hip_runtime.h>
#include <hip/hip_bf16.h>
#include <math.h>

#define N_ROWS 8192   // SIZE
#define N_COLS 1024   // M

typedef float f32x4 __attribute__((ext_vector_type(4)));  // native vec for nontemporal builtin

// ---------------- Primary path: K1 writes exp(x) as bf16 for K2 ----------------

// K1e: ps[b][j] = bf16( sum_{i in [32b,32b+32)} exp(x[i][j]) ); also
//      ebf[i][j] = bf16(exp(x[i][j])) so K2 never re-reads x from HBM.
__global__ __launch_bounds__(1024) void colsum_part_e(
    const float* __restrict__ x, __hip_bfloat16* __restrict__ ps,
    __hip_bfloat162* __restrict__ ebf2) {
    const int b    = blockIdx.x;
    const int t    = threadIdx.x;
    const int col0 = (t & 255) * 4;
    const int rg   = t >> 8;            // 0..3
    const int row0 = b * 32 + rg * 8;

    float4 s4 = make_float4(0.f, 0.f, 0.f, 0.f);
#pragma unroll
    for (int k = 0; k < 8; ++k) {
        const int row = row0 + k;
        const float4 v = *reinterpret_cast<const float4*>(
            x + (size_t)row * N_COLS + col0);
        float4 e;
        e.x = __expf(v.x); e.y = __expf(v.y);
        e.z = __expf(v.z); e.w = __expf(v.w);
        __hip_bfloat162 h0, h1;
        h0.x = __float2bfloat16(e.x); h0.y = __float2bfloat16(e.y);
        h1.x = __float2bfloat16(e.z); h1.y = __float2bfloat16(e.w);
        const size_t p2 = ((size_t)row * N_COLS + col0) >> 1;
        ebf2[p2]     = h0;
        ebf2[p2 + 1] = h1;
        s4.x += e.x; s4.y += e.y; s4.z += e.z; s4.w += e.w;
    }
    __shared__ float red[4][N_COLS];    // 16 KB
    *reinterpret_cast<float4*>(&red[rg][col0]) = s4;
    __syncthreads();
    const float s = red[0][t] + red[1][t] + red[2][t] + red[3][t];
    ps[(size_t)b * N_COLS + t] = __float2bfloat16(s);
}

// K2e: 8 col-stripes x 32 row-blocks, 1024 threads (round-12 phase A exact).
// Phase B reads bf16 e instead of f32 x: no exp, half the read bytes.
__global__ __launch_bounds__(1024) void merge_finalize_e(
    const float* __restrict__ diag, const __hip_bfloat16* __restrict__ ps,
    const __hip_bfloat162* __restrict__ ebf2, float* __restrict__ out) {
    const int cs = blockIdx.x & 7;      // stripe 0..7
    const int rb = blockIdx.x >> 3;     // row-block 0..31
    const int c0 = cs * 128;
    const int t  = threadIdx.x;

    __shared__ float red[16][128];      // 8 KB
    __shared__ float S[128];            // 512 B
    {
        const int cg = t >> 6;          // chunk-group 0..15 (16 chunks each)
        const int cp = t & 63;          // col-pair within stripe
        const __hip_bfloat162* ps2 = reinterpret_cast<const __hip_bfloat162*>(ps);
        float s0 = 0.f, s1 = 0.f;
#pragma unroll 8
        for (int k = 0; k < 16; ++k) {
            const __hip_bfloat162 p =
                ps2[(size_t)(cg * 16 + k) * (N_COLS / 2) + cs * 64 + cp];
            s0 += __bfloat162float(p.x);
            s1 += __bfloat162float(p.y);
        }
        red[cg][2 * cp]     = s0;
        red[cg][2 * cp + 1] = s1;
    }
    __syncthreads();
    if (t < 128) {
        float s = 0.f;
#pragma unroll
        for (int g = 0; g < 16; ++g) s += red[g][t];
        S[t] = s;
    }
    __syncthreads();

    const int rr = t >> 5;
    const int cv = t & 31;
    const int col = c0 + 4 * cv;
    const float4 Sj = *reinterpret_cast<const float4*>(&S[4 * cv]);
    const int r0 = rb * 256 + rr;

#pragma unroll
    for (int k = 0; k < 8; ++k) {
        const int row = r0 + k * 32;
        const float E = __expf(diag[row]) - 1.f;   // wave-uniform
        const size_t p2 = ((size_t)row * N_COLS + col) >> 1;
        const __hip_bfloat162 h0 = ebf2[p2];
        const __hip_bfloat162 h1 = ebf2[p2 + 1];
        f32x4 o;
        o.x = __logf(fmaf(E, __bfloat162float(h0.x), Sj.x));
        o.y = __logf(fmaf(E, __bfloat162float(h0.y), Sj.y));
        o.z = __logf(fmaf(E, __bfloat162float(h1.x), Sj.z));
        o.w = __logf(fmaf(E, __bfloat162float(h1.y), Sj.w));
        __builtin_nontemporal_store(
            o, reinterpret_cast<f32x4*>(out + (size_t)row * N_COLS + col));
    }
}

// ---------------- Fallback path (round-12 exact, proven 24.7 us) ----------------

__global__ __launch_bounds__(1024) void colsum_part(
    const float* __restrict__ x, __hip_bfloat16* __restrict__ ps) {
    const int b    = blockIdx.x;
    const int t    = threadIdx.x;
    const int col0 = (t & 255) * 4;
    const int rg   = t >> 8;
    const int row0 = b * 32 + rg * 8;

    float4 s4 = make_float4(0.f, 0.f, 0.f, 0.f);
#pragma unroll
    for (int k = 0; k < 8; ++k) {
        const float4 v = *reinterpret_cast<const float4*>(
            x + (size_t)(row0 + k) * N_COLS + col0);
        s4.x += __expf(v.x); s4.y += __expf(v.y);
        s4.z += __expf(v.z); s4.w += __expf(v.w);
    }
    __shared__ float red[4][N_COLS];
    *reinterpret_cast<float4*>(&red[rg][col0]) = s4;
    __syncthreads();
    const float s = red[0][t] + red[1][t] + red[2][t] + red[3][t];
    ps[(size_t)b * N_COLS + t] = __float2bfloat16(s);
}

__global__ __launch_bounds__(1024) void merge_finalize(
    const float* __restrict__ x, const float* __restrict__ diag,
    const __hip_bfloat16* __restrict__ ps, float* __restrict__ out) {
    const int cs = blockIdx.x & 7;
    const int rb = blockIdx.x >> 3;
    const int c0 = cs * 128;
    const int t  = threadIdx.x;

    __shared__ float red[16][128];
    __shared__ float S[128];
    {
        const int cg = t >> 6;
        const int cp = t & 63;
        const __hip_bfloat162* ps2 = reinterpret_cast<const __hip_bfloat162*>(ps);
        float s0 = 0.f, s1 = 0.f;
#pragma unroll 8
        for (int k = 0; k < 16; ++k) {
            const __hip_bfloat162 p =
                ps2[(size_t)(cg * 16 + k) * (N_COLS / 2) + cs * 64 + cp];
            s0 += __bfloat162float(p.x);
            s1 += __bfloat162float(p.y);
        }
        red[cg][2 * cp]     = s0;
        red[cg][2 * cp + 1] = s1;
    }
    __syncthreads();
    if (t < 128) {
        float s = 0.f;
#pragma unroll
        for (int g = 0; g < 16; ++g) s += red[g][t];
        S[t] = s;
    }
    __syncthreads();

    const int rr = t >> 5;
    const int cv = t & 31;
    const int col = c0 + 4 * cv;
    const float4 Sj = *reinterpret_cast<const float4*>(&S[4 * cv]);
    const int r0 = rb * 256 + rr;

#pragma unroll
    for (int k = 0; k < 8; ++k) {
        const int row = r0 + k * 32;
        const float E = __expf(diag[row]) - 1.f;
        const size_t off = (size_t)row * N_COLS + col;
        const float4 v = *reinterpret_cast<const float4*>(x + off);
        f32x4 o;
        o.x = __logf(fmaf(E, __expf(v.x), Sj.x));
        o.y = __logf(fmaf(E, __expf(v.y), Sj.y));
        o.z = __logf(fmaf(E, __expf(v.z), Sj.z));
        o.w = __logf(fmaf(E, __expf(v.w), Sj.w));
        __builtin_nontemporal_store(o, reinterpret_cast<f32x4*>(out + off));
    }
}

extern "C" void kernel_launch(void* const* d_in, const int* in_sizes, int n_in,
                              void* d_out, int out_size, void* d_ws, size_t ws_size,
                              hipStream_t stream) {
    const float* x    = (const float*)d_in[0];   // [8192, 1024] f32
    const float* diag = (const float*)d_in[1];   // [8192] f32
    float* out = (float*)d_out;                  // [8192, 1024] f32

    __hip_bfloat16* ps = (__hip_bfloat16*)d_ws;            // 512 KB
    const size_t need = (size_t)(256 * N_COLS) * 2          // ps
                      + (size_t)N_ROWS * N_COLS * 2;        // ebf
    if (ws_size >= need) {
        __hip_bfloat162* ebf2 =
            reinterpret_cast<__hip_bfloat162*>(ps + 256 * N_COLS);
        colsum_part_e<<<256, 1024, 0, stream>>>(x, ps, ebf2);
        merge_finalize_e<<<256, 1024, 0, stream>>>(diag, ps, ebf2, out);
    } else {
        colsum_part<<<256, 1024, 0, stream>>>(x, ps);
        merge_finalize<<<256, 1024, 0, stream>>>(x, diag, ps, out);
    }
}